// Round 10
// baseline (134.439 us; speedup 1.0000x reference)
//
#include <hip/hip_runtime.h>
#include <hip/hip_bf16.h>
#include <math.h>

#define FIN 128
#define NHEAD 4
#define CH 128          // H*F
#define ELU_A 0.2f

#define BSHIFT 8                 // bucket = tgt >> 8  (256 nodes per bucket)
#define NB 196                   // ceil(50000 / 256)
#define CAP 16384                // max edges per bucket (mean ~8192, sd ~90)
#define T_EDGES 2048             // edges per partition block (256 thr x 8)

typedef unsigned int uint32;
typedef __attribute__((ext_vector_type(8))) short short8;   // 8 bf16 (4 VGPRs)
typedef __attribute__((ext_vector_type(4))) float f32x4;

__device__ __forceinline__ float bf16lo(uint32 u) {
    union { uint32 i; float f; } c; c.i = u << 16; return c.f;
}
__device__ __forceinline__ float bf16hi(uint32 u) {
    union { uint32 i; float f; } c; c.i = u & 0xffff0000u; return c.f;
}
__device__ __forceinline__ unsigned short f2b(float f) {   // fp32 -> bf16 RNE
    union { float f; uint32 u; } c; c.f = f;
    uint32 u = c.u;
    return (unsigned short)((u + 0x7fffu + ((u >> 16) & 1u)) >> 16);
}

// ---------------- K1: partition edges into buckets  ∪  wprep ---------------
// Blocks [0, PB): partition. Block PB (last): Wt[n][k] = bf16(W[k][n]).
__global__ __launch_bounds__(256) void partition_kernel(
    const int2* __restrict__ ei2, int* __restrict__ bcnt,
    uint32* __restrict__ ebuck, const float* __restrict__ W,
    unsigned short* __restrict__ Wt, int E)
{
    if (blockIdx.x == gridDim.x - 1) {
        // ---- wprep role (no LDS): 128 n x 16 k-octets = 2048 tasks ----
        for (int task = threadIdx.x; task < CH * (FIN / 8); task += 256) {
            int n  = task >> 4;
            int k0 = (task & 15) * 8;
            unsigned short v[8];
#pragma unroll
            for (int j = 0; j < 8; ++j) v[j] = f2b(W[(size_t)(k0 + j) * CH + n]);
            *(uint4*)&Wt[(size_t)n * FIN + k0] = *(uint4*)v;
        }
        return;
    }

    __shared__ uint32 stage[T_EDGES];                       // 8 KB
    __shared__ int hist[256], scanbuf[256], loff[256], cnt2[256], base[256];
    const int tid = threadIdx.x;
    const int e0 = blockIdx.x * T_EDGES;
    const int tile = min(T_EDGES, E - e0);

    hist[tid] = 0; cnt2[tid] = 0;
    __syncthreads();

    uint32 rec[8];
#pragma unroll
    for (int j = 0; j < 8; ++j) {
        int idx = e0 + j * 256 + tid;
        if (idx < E) {
            int2 p = ei2[idx];
            rec[j] = (uint32)p.x | ((uint32)p.y << 16);
            atomicAdd(&hist[p.y >> BSHIFT], 1);
        } else rec[j] = 0xFFFFFFFFu;
    }
    __syncthreads();

    scanbuf[tid] = hist[tid];
    __syncthreads();
    for (int off = 1; off < 256; off <<= 1) {
        int v = (tid >= off) ? scanbuf[tid - off] : 0;
        __syncthreads();
        scanbuf[tid] += v;
        __syncthreads();
    }
    loff[tid] = scanbuf[tid] - hist[tid];
    if (tid < NB && hist[tid] > 0)
        base[tid] = tid * CAP + atomicAdd(&bcnt[tid], hist[tid]);
    __syncthreads();

#pragma unroll
    for (int j = 0; j < 8; ++j) {
        if (rec[j] != 0xFFFFFFFFu) {
            int b = rec[j] >> (16 + BSHIFT);
            int r = atomicAdd(&cnt2[b], 1);
            stage[loff[b] + r] = rec[j];
        }
    }
    __syncthreads();

    for (int i = tid; i < tile; i += 256) {
        uint32 rc = stage[i];
        int b = rc >> (16 + BSHIFT);
        ebuck[(size_t)base[b] + (i - loff[b])] = rc;
    }
}

// ---------------- K2: MFMA GEMM + fused scores  ∪  bscan --------------------
// Blocks [0, GB): gemm. Block GB (last): exclusive scan of bcnt[196].
__global__ __launch_bounds__(256) void gemm_bscan_kernel(
    const float* __restrict__ x, const unsigned short* __restrict__ Wt,
    unsigned short* __restrict__ xpb, const float* __restrict__ a_src,
    const float* __restrict__ a_tgt, float* __restrict__ s_src,
    float* __restrict__ s_tgt, const int* __restrict__ bcnt,
    int* __restrict__ bbase, int N)
{
    __shared__ unsigned short cbuf[4][16][132];   // 16.9 KB (also reused by bscan)

    if (blockIdx.x == gridDim.x - 1) {
        // ---- bscan role (reuse cbuf as int[256]) ----
        int* s = (int*)&cbuf[0][0][0];
        const int t = threadIdx.x;
        int v = (t < NB) ? bcnt[t] : 0;
        s[t] = v;
        __syncthreads();
        for (int off = 1; off < 256; off <<= 1) {
            int u = (t >= off) ? s[t - off] : 0;
            __syncthreads();
            s[t] += u;
            __syncthreads();
        }
        if (t < NB) bbase[t] = s[t] - v;
        return;
    }

    const int lane = threadIdx.x & 63;
    const int wid  = threadIdx.x >> 6;
    const int rowbase = blockIdx.x * 64 + wid * 16;

    const int rr   = min(rowbase + (lane & 15), N - 1);   // clamped A row
    const int krow = (lane >> 4) * 8;                     // k base within step

    f32x4 acc[8];
#pragma unroll
    for (int c = 0; c < 8; ++c) acc[c] = (f32x4){0.f, 0.f, 0.f, 0.f};

#pragma unroll
    for (int s = 0; s < 4; ++s) {
        const int koff = s * 32 + krow;
        const float* xr = x + (size_t)rr * FIN + koff;
        float4 p0 = *(const float4*)xr;
        float4 p1 = *(const float4*)(xr + 4);
        short8 af;
        af[0] = (short)f2b(p0.x); af[1] = (short)f2b(p0.y);
        af[2] = (short)f2b(p0.z); af[3] = (short)f2b(p0.w);
        af[4] = (short)f2b(p1.x); af[5] = (short)f2b(p1.y);
        af[6] = (short)f2b(p1.z); af[7] = (short)f2b(p1.w);
#pragma unroll
        for (int c = 0; c < 8; ++c) {
            const short8 bf = *(const short8*)&Wt[(size_t)(c * 16 + (lane & 15)) * FIN + koff];
            acc[c] = __builtin_amdgcn_mfma_f32_16x16x32_bf16(af, bf, acc[c], 0, 0, 0);
        }
    }

    // C frags -> LDS (D mapping: col=lane&15, row=(lane>>4)*4+reg; m89)
#pragma unroll
    for (int c = 0; c < 8; ++c)
#pragma unroll
        for (int r = 0; r < 4; ++r)
            cbuf[wid][(lane >> 4) * 4 + r][c * 16 + (lane & 15)] = f2b(acc[c][r]);
    __syncthreads();

    // coalesced bf16 store of the 16-row tile
    for (int r = 0; r < 16; ++r) {
        int row = rowbase + r;
        if (row < N) {
            uint32 v = *(const uint32*)&cbuf[wid][r][lane * 2];
            *(uint32*)&xpb[(size_t)row * CH + lane * 2] = v;
        }
    }

    // fused per-node scores from cbuf: lane -> (row=lane>>2, head=lane&3)
    {
        const int srow = lane >> 2;
        const int sh   = lane & 3;
        const unsigned short* cp = &cbuf[wid][srow][sh * 32];
        const float* as = a_src + sh * 32;
        const float* at = a_tgt + sh * 32;
        float ps = 0.f, pt = 0.f;
#pragma unroll
        for (int q = 0; q < 4; ++q) {
            uint4 u = *(const uint4*)&cp[q * 8];          // 8 bf16
            float4 a0 = *(const float4*)&as[q * 8];
            float4 a1 = *(const float4*)&as[q * 8 + 4];
            float4 b0 = *(const float4*)&at[q * 8];
            float4 b1 = *(const float4*)&at[q * 8 + 4];
            float l0 = bf16lo(u.x), h0 = bf16hi(u.x);
            float l1 = bf16lo(u.y), h1 = bf16hi(u.y);
            float l2 = bf16lo(u.z), h2 = bf16hi(u.z);
            float l3 = bf16lo(u.w), h3 = bf16hi(u.w);
            ps += l0*a0.x + h0*a0.y + l1*a0.z + h1*a0.w
                + l2*a1.x + h2*a1.y + l3*a1.z + h3*a1.w;
            pt += l0*b0.x + h0*b0.y + l1*b0.z + h1*b0.w
                + l2*b1.x + h2*b1.y + l3*b1.z + h3*b1.w;
        }
        int node = rowbase + srow;
        if (node < N) {
            s_src[(size_t)node * NHEAD + sh] = ps;
            s_tgt[(size_t)node * NHEAD + sh] = pt;
        }
    }
}

// ---------------- K3: fine scatter; derives deg/rowptr locally --------------
__global__ __launch_bounds__(1024) void fine_scatter_kernel(
    const uint32* __restrict__ ebuck, const int* __restrict__ bcnt,
    const int* __restrict__ bbase, int* __restrict__ deg,
    int* __restrict__ rowptr, int* __restrict__ srcs, int N)
{
    __shared__ int ldeg[256], psum[256], lcur[256];
    const int b = blockIdx.x;
    const int tid = threadIdx.x;
    if (tid < 256) ldeg[tid] = 0;
    __syncthreads();

    const int cnt = bcnt[b];
    const uint32* rp = ebuck + (size_t)b * CAP;

    for (int i = tid; i < cnt; i += 1024)
        atomicAdd(&ldeg[(rp[i] >> 16) & 255], 1);
    __syncthreads();

    if (tid < 256) psum[tid] = ldeg[tid];
    __syncthreads();
    for (int off = 1; off < 256; off <<= 1) {
        int u = 0;
        if (tid < 256 && tid >= off) u = psum[tid - off];
        __syncthreads();
        if (tid < 256) psum[tid] += u;
        __syncthreads();
    }

    const int gb = bbase[b];
    if (tid < 256) {
        int pref = gb + psum[tid] - ldeg[tid];
        lcur[tid] = pref;
        int node = b * 256 + tid;
        if (node < N) { deg[node] = ldeg[tid]; rowptr[node] = pref; }
    }
    __syncthreads();

    for (int i = tid; i < cnt; i += 1024) {
        uint32 rc = rp[i];
        int pos = atomicAdd(&lcur[(rc >> 16) & 255], 1);
        srcs[pos] = rc & 0xffff;
    }
}

// ---------------- K4: per-node aggregation ----------------------------------
__global__ __launch_bounds__(256) void aggregate_kernel(
    const int* __restrict__ srcs, const int* __restrict__ rowptr,
    const int* __restrict__ deg, const float* __restrict__ s_src,
    const float* __restrict__ s_tgt, const uint32* __restrict__ xpb,
    float* __restrict__ out, int N)
{
    const int lane = threadIdx.x & 63;
    const int wid  = __builtin_amdgcn_readfirstlane(threadIdx.x >> 6);
    const int t = blockIdx.x * 4 + wid;
    if (t >= N) return;

    const int start = __builtin_amdgcn_readfirstlane(rowptr[t]);
    const int d     = __builtin_amdgcn_readfirstlane(deg[t]);
    const int h     = lane >> 4;
    const int cj    = lane & 7;
    const int chh   = (lane >> 3) & 3;

    const float st_c = s_tgt[(size_t)t * NHEAD + chh];
    const float st_h = s_tgt[(size_t)t * NHEAD + h];
    const int bb = h * 8;

    float accx = 0.0f, accy = 0.0f, dsum = 0.0f;
    int k = 0;

    for (; k + 8 <= d; k += 8) {
        int   sv = srcs[start + k + cj];
        float a  = s_src[(size_t)sv * NHEAD + chh];
        float v  = a + st_c;
        float u  = v > 0.0f ? v : ELU_A * (__expf(v) - 1.0f);
        float e  = __expf(u);

        int s0 = srcs[start + k + 0], s1 = srcs[start + k + 1];
        int s2 = srcs[start + k + 2], s3 = srcs[start + k + 3];
        int s4 = srcs[start + k + 4], s5 = srcs[start + k + 5];
        int s6 = srcs[start + k + 6], s7 = srcs[start + k + 7];

        uint32 x0 = xpb[(size_t)s0 * 64 + lane];
        uint32 x1 = xpb[(size_t)s1 * 64 + lane];
        uint32 x2 = xpb[(size_t)s2 * 64 + lane];
        uint32 x3 = xpb[(size_t)s3 * 64 + lane];
        uint32 x4 = xpb[(size_t)s4 * 64 + lane];
        uint32 x5 = xpb[(size_t)s5 * 64 + lane];
        uint32 x6 = xpb[(size_t)s6 * 64 + lane];
        uint32 x7 = xpb[(size_t)s7 * 64 + lane];

        float e0 = __shfl(e, bb + 0), e1 = __shfl(e, bb + 1);
        float e2 = __shfl(e, bb + 2), e3 = __shfl(e, bb + 3);
        float e4 = __shfl(e, bb + 4), e5 = __shfl(e, bb + 5);
        float e6 = __shfl(e, bb + 6), e7 = __shfl(e, bb + 7);

#define ACC(E, X) { dsum += (E); accx += (E) * bf16lo(X); accy += (E) * bf16hi(X); }
        ACC(e0, x0) ACC(e1, x1) ACC(e2, x2) ACC(e3, x3)
        ACC(e4, x4) ACC(e5, x5) ACC(e6, x6) ACC(e7, x7)
#undef ACC
    }

    for (; k < d; ++k) {
        int   s  = srcs[start + k];
        float a  = s_src[(size_t)s * NHEAD + h];
        uint32 xv = xpb[(size_t)s * 64 + lane];
        float v = a + st_h;
        float u = v > 0.0f ? v : ELU_A * (__expf(v) - 1.0f);
        float e = __expf(u);
        dsum += e; accx += e * bf16lo(xv); accy += e * bf16hi(xv);
    }

    float inv = (d > 0) ? 1.0f / dsum : 0.0f;
    float2 o = make_float2(accx * inv, accy * inv);
    *(float2*)&out[(size_t)t * CH + lane * 2] = o;
}

extern "C" void kernel_launch(void* const* d_in, const int* in_sizes, int n_in,
                              void* d_out, int out_size, void* d_ws, size_t ws_size,
                              hipStream_t stream)
{
    const float* x     = (const float*)d_in[0];
    const float* W     = (const float*)d_in[1];
    const float* a_src = (const float*)d_in[2];
    const float* a_tgt = (const float*)d_in[3];
    const int*   ei    = (const int*)d_in[4];

    const int N = in_sizes[0] / FIN;      // 50000
    const int E = in_sizes[4] / 2;        // 1600000
    const int PB = (E + T_EDGES - 1) / T_EDGES;   // 782 partition blocks
    const int GB = (N + 63) / 64;                 // 782 gemm blocks

    char* ws = (char*)d_ws;
    unsigned short* xpb = (unsigned short*)ws;  ws += (size_t)N * CH * sizeof(unsigned short);
    unsigned short* Wt  = (unsigned short*)ws;  ws += (size_t)FIN * CH * sizeof(unsigned short);
    float* s_src  = (float*)ws;                 ws += (size_t)N * NHEAD * sizeof(float);
    float* s_tgt  = (float*)ws;                 ws += (size_t)N * NHEAD * sizeof(float);
    int*   deg    = (int*)ws;                   ws += (size_t)N * sizeof(int);
    int*   bcnt   = (int*)ws;                   ws += (size_t)NB * sizeof(int);
    int*   bbase  = (int*)ws;                   ws += (size_t)NB * sizeof(int);
    int*   rowptr = (int*)ws;                   ws += (size_t)N * sizeof(int);
    int*   srcs   = (int*)ws;                   ws += (size_t)E * sizeof(int);
    uint32* ebuck = (uint32*)ws;                ws += (size_t)NB * CAP * sizeof(uint32);

    float* out = (float*)d_out;
    const int2* ei2 = (const int2*)ei;

    hipMemsetAsync(bcnt, 0, (size_t)NB * sizeof(int), stream);

    partition_kernel<<<PB + 1, 256, 0, stream>>>(ei2, bcnt, ebuck, W, Wt, E);
    gemm_bscan_kernel<<<GB + 1, 256, 0, stream>>>(
        x, Wt, xpb, a_src, a_tgt, s_src, s_tgt, bcnt, bbase, N);
    fine_scatter_kernel<<<NB, 1024, 0, stream>>>(
        ebuck, bcnt, bbase, deg, rowptr, srcs, N);
    aggregate_kernel<<<(N + 3) / 4, 256, 0, stream>>>(
        srcs, rowptr, deg, s_src, s_tgt, (const uint32*)xpb, out, N);
}

// Round 11
// 120.497 us; speedup vs baseline: 1.1157x; 1.1157x over previous
//
#include <hip/hip_runtime.h>
#include <hip/hip_bf16.h>
#include <math.h>

#define FIN 128
#define NHEAD 4
#define CH 128          // H*F
#define ELU_A 0.2f

#define BSHIFT 8                 // bucket = tgt >> 8  (256 nodes per bucket)
#define NB 196                   // ceil(50000 / 256)
#define CAP 16384                // max edges per bucket (mean ~8192, sd ~90)
#define T_EDGES 2048             // edges per partition block (256 thr x 8)

typedef unsigned int uint32;
typedef __attribute__((ext_vector_type(8))) short short8;   // 8 bf16 (4 VGPRs)
typedef __attribute__((ext_vector_type(4))) float f32x4;

__device__ __forceinline__ float bf16lo(uint32 u) {
    union { uint32 i; float f; } c; c.i = u << 16; return c.f;
}
__device__ __forceinline__ float bf16hi(uint32 u) {
    union { uint32 i; float f; } c; c.i = u & 0xffff0000u; return c.f;
}
__device__ __forceinline__ unsigned short f2b(float f) {   // fp32 -> bf16 RNE
    union { float f; uint32 u; } c; c.f = f;
    uint32 u = c.u;
    return (unsigned short)((u + 0x7fffu + ((u >> 16) & 1u)) >> 16);
}

// ---------------- MegaK1: partition (blocks [0,PB)) ∪ gemm (blocks [PB,..)) -
// Independent chains overlapped in one dispatch. Gemm self-stages W->bf16 LDS
// (no global Wt, no wprep ordering hazard); cbuf overlays wt after a barrier.
union SMem {
    struct {
        uint32 stage[T_EDGES];                       // 8 KB
        int hist[256], scanbuf[256], loff[256], cnt2[256], base[256];
    } p;                                             // 13 KB
    unsigned short wt[128][136];                     // 34.8 KB (bf16 W^T, +8 pad)
    unsigned short cbuf[4][16][132];                 // 16.9 KB (overlays wt)
};

__global__ __launch_bounds__(256) void mega_kernel(
    const int2* __restrict__ ei2, int* __restrict__ bcnt,
    uint32* __restrict__ ebuck, const float* __restrict__ x,
    const float* __restrict__ W, unsigned short* __restrict__ xpb,
    const float* __restrict__ a_src, const float* __restrict__ a_tgt,
    float* __restrict__ s_src, float* __restrict__ s_tgt,
    int E, int N, int PB)
{
    __shared__ SMem sm;
    const int tid = threadIdx.x;

    if ((int)blockIdx.x < PB) {
        // ================= partition role =================
        const int e0 = blockIdx.x * T_EDGES;
        const int tile = min(T_EDGES, E - e0);

        sm.p.hist[tid] = 0; sm.p.cnt2[tid] = 0;
        __syncthreads();

        uint32 rec[8];
#pragma unroll
        for (int j = 0; j < 8; ++j) {
            int idx = e0 + j * 256 + tid;
            if (idx < E) {
                int2 p = ei2[idx];
                rec[j] = (uint32)p.x | ((uint32)p.y << 16);
                atomicAdd(&sm.p.hist[p.y >> BSHIFT], 1);
            } else rec[j] = 0xFFFFFFFFu;
        }
        __syncthreads();

        sm.p.scanbuf[tid] = sm.p.hist[tid];
        __syncthreads();
        for (int off = 1; off < 256; off <<= 1) {
            int v = (tid >= off) ? sm.p.scanbuf[tid - off] : 0;
            __syncthreads();
            sm.p.scanbuf[tid] += v;
            __syncthreads();
        }
        sm.p.loff[tid] = sm.p.scanbuf[tid] - sm.p.hist[tid];
        if (tid < NB && sm.p.hist[tid] > 0)
            sm.p.base[tid] = tid * CAP + atomicAdd(&bcnt[tid], sm.p.hist[tid]);
        __syncthreads();

#pragma unroll
        for (int j = 0; j < 8; ++j) {
            if (rec[j] != 0xFFFFFFFFu) {
                int b = rec[j] >> (16 + BSHIFT);
                int r = atomicAdd(&sm.p.cnt2[b], 1);
                sm.p.stage[sm.p.loff[b] + r] = rec[j];
            }
        }
        __syncthreads();

        for (int i = tid; i < tile; i += 256) {
            uint32 rc = sm.p.stage[i];
            int b = rc >> (16 + BSHIFT);
            ebuck[(size_t)sm.p.base[b] + (i - sm.p.loff[b])] = rc;
        }
        return;
    }

    // ================= gemm + fused scores role =================
    const int gb = blockIdx.x - PB;

    // stage W (fp32 [k][n]) -> sm.wt (bf16 [n][k], row pad 136)
    for (int i = tid; i < FIN * CH / 2; i += 256) {
        int n  = i & 127;          // coalesced in n
        int k2 = i >> 7;           // k pair 2*k2, 2*k2+1
        float w0 = W[(size_t)(2 * k2 + 0) * CH + n];
        float w1 = W[(size_t)(2 * k2 + 1) * CH + n];
        uint32 pk = (uint32)f2b(w0) | ((uint32)f2b(w1) << 16);
        *(uint32*)&sm.wt[n][2 * k2] = pk;
    }
    __syncthreads();

    const int lane = tid & 63;
    const int wid  = tid >> 6;
    const int rowbase = gb * 64 + wid * 16;

    const int rr   = min(rowbase + (lane & 15), N - 1);   // clamped A row
    const int krow = (lane >> 4) * 8;

    f32x4 acc[8];
#pragma unroll
    for (int c = 0; c < 8; ++c) acc[c] = (f32x4){0.f, 0.f, 0.f, 0.f};

#pragma unroll
    for (int s = 0; s < 4; ++s) {
        const int koff = s * 32 + krow;
        const float* xr = x + (size_t)rr * FIN + koff;
        float4 p0 = *(const float4*)xr;
        float4 p1 = *(const float4*)(xr + 4);
        short8 af;
        af[0] = (short)f2b(p0.x); af[1] = (short)f2b(p0.y);
        af[2] = (short)f2b(p0.z); af[3] = (short)f2b(p0.w);
        af[4] = (short)f2b(p1.x); af[5] = (short)f2b(p1.y);
        af[6] = (short)f2b(p1.z); af[7] = (short)f2b(p1.w);
#pragma unroll
        for (int c = 0; c < 8; ++c) {
            const short8 bf = *(const short8*)&sm.wt[c * 16 + (lane & 15)][koff];
            acc[c] = __builtin_amdgcn_mfma_f32_16x16x32_bf16(af, bf, acc[c], 0, 0, 0);
        }
    }
    __syncthreads();   // wt no longer needed; cbuf overlays it

    // C frags -> LDS (D mapping: col=lane&15, row=(lane>>4)*4+reg; m89)
#pragma unroll
    for (int c = 0; c < 8; ++c)
#pragma unroll
        for (int r = 0; r < 4; ++r)
            sm.cbuf[wid][(lane >> 4) * 4 + r][c * 16 + (lane & 15)] = f2b(acc[c][r]);
    __syncthreads();

    for (int r = 0; r < 16; ++r) {
        int row = rowbase + r;
        if (row < N) {
            uint32 v = *(const uint32*)&sm.cbuf[wid][r][lane * 2];
            *(uint32*)&xpb[(size_t)row * CH + lane * 2] = v;
        }
    }

    {   // fused per-node scores: lane -> (row=lane>>2, head=lane&3)
        const int srow = lane >> 2;
        const int sh   = lane & 3;
        const unsigned short* cp = &sm.cbuf[wid][srow][sh * 32];
        const float* as = a_src + sh * 32;
        const float* at = a_tgt + sh * 32;
        float ps = 0.f, pt = 0.f;
#pragma unroll
        for (int q = 0; q < 4; ++q) {
            uint4 u = *(const uint4*)&cp[q * 8];
            float4 a0 = *(const float4*)&as[q * 8];
            float4 a1 = *(const float4*)&as[q * 8 + 4];
            float4 b0 = *(const float4*)&at[q * 8];
            float4 b1 = *(const float4*)&at[q * 8 + 4];
            float l0 = bf16lo(u.x), h0 = bf16hi(u.x);
            float l1 = bf16lo(u.y), h1 = bf16hi(u.y);
            float l2 = bf16lo(u.z), h2 = bf16hi(u.z);
            float l3 = bf16lo(u.w), h3 = bf16hi(u.w);
            ps += l0*a0.x + h0*a0.y + l1*a0.z + h1*a0.w
                + l2*a1.x + h2*a1.y + l3*a1.z + h3*a1.w;
            pt += l0*b0.x + h0*b0.y + l1*b0.z + h1*b0.w
                + l2*b1.x + h2*b1.y + l3*b1.z + h3*b1.w;
        }
        int node = rowbase + srow;
        if (node < N) {
            s_src[(size_t)node * NHEAD + sh] = ps;
            s_tgt[(size_t)node * NHEAD + sh] = pt;
        }
    }
}

// ---------------- K2: fine scatter; inline bbase; derives deg/rowptr --------
__global__ __launch_bounds__(1024) void fine_scatter_kernel(
    const uint32* __restrict__ ebuck, const int* __restrict__ bcnt,
    int* __restrict__ deg, int* __restrict__ rowptr,
    int* __restrict__ srcs, int N)
{
    __shared__ int ldeg[256], psum[256], lcur[256], red[256];
    const int b = blockIdx.x;
    const int tid = threadIdx.x;

    // inline bbase: gb = sum bcnt[0..b)
    if (tid < 256) {
        red[tid]  = (tid < b) ? bcnt[tid] : 0;
        ldeg[tid] = 0;
    }
    __syncthreads();
    for (int off = 128; off >= 1; off >>= 1) {
        if (tid < off) red[tid] += red[tid + off];
        __syncthreads();
    }
    const int gb = red[0];

    const int cnt = bcnt[b];
    const uint32* rp = ebuck + (size_t)b * CAP;

    for (int i = tid; i < cnt; i += 1024)
        atomicAdd(&ldeg[(rp[i] >> 16) & 255], 1);
    __syncthreads();

    if (tid < 256) psum[tid] = ldeg[tid];
    __syncthreads();
    for (int off = 1; off < 256; off <<= 1) {
        int u = 0;
        if (tid < 256 && tid >= off) u = psum[tid - off];
        __syncthreads();
        if (tid < 256) psum[tid] += u;
        __syncthreads();
    }

    if (tid < 256) {
        int pref = gb + psum[tid] - ldeg[tid];
        lcur[tid] = pref;
        int node = b * 256 + tid;
        if (node < N) { deg[node] = ldeg[tid]; rowptr[node] = pref; }
    }
    __syncthreads();

    for (int i = tid; i < cnt; i += 1024) {
        uint32 rc = rp[i];
        int pos = atomicAdd(&lcur[(rc >> 16) & 255], 1);
        srcs[pos] = rc & 0xffff;
    }
}

// ---------------- K3: per-node aggregation ----------------------------------
// 16-edge tier: all 64 lanes compute e (lane = edge (lane&15) x head (lane>>4),
// broadcast-source head == consumer head). Then 8-edge tier, then scalar tail.
__global__ __launch_bounds__(256) void aggregate_kernel(
    const int* __restrict__ srcs, const int* __restrict__ rowptr,
    const int* __restrict__ deg, const float* __restrict__ s_src,
    const float* __restrict__ s_tgt, const uint32* __restrict__ xpb,
    float* __restrict__ out, int N)
{
    const int lane = threadIdx.x & 63;
    const int wid  = __builtin_amdgcn_readfirstlane(threadIdx.x >> 6);
    const int t = blockIdx.x * 4 + wid;
    if (t >= N) return;

    const int start = __builtin_amdgcn_readfirstlane(rowptr[t]);
    const int d     = __builtin_amdgcn_readfirstlane(deg[t]);
    const int h     = lane >> 4;
    const float st_h = s_tgt[(size_t)t * NHEAD + h];

    float accx = 0.0f, accy = 0.0f, dsum = 0.0f;
    int k = 0;

#define ACC(E, X) { dsum += (E); accx += (E) * bf16lo(X); accy += (E) * bf16hi(X); }

    // ---- 16-edge tier ----
    const int cj16 = lane & 15;
    const int bb16 = h * 16;
    for (; k + 16 <= d; k += 16) {
        int   sv = srcs[start + k + cj16];
        float a  = s_src[(size_t)sv * NHEAD + h];
        float v  = a + st_h;
        float u  = v > 0.0f ? v : ELU_A * (__expf(v) - 1.0f);
        float e  = __expf(u);

        int s0 = srcs[start + k + 0],  s1 = srcs[start + k + 1];
        int s2 = srcs[start + k + 2],  s3 = srcs[start + k + 3];
        int s4 = srcs[start + k + 4],  s5 = srcs[start + k + 5];
        int s6 = srcs[start + k + 6],  s7 = srcs[start + k + 7];
        int s8 = srcs[start + k + 8],  s9 = srcs[start + k + 9];
        int sa = srcs[start + k + 10], sb = srcs[start + k + 11];
        int sc = srcs[start + k + 12], sd = srcs[start + k + 13];
        int se = srcs[start + k + 14], sf = srcs[start + k + 15];

        uint32 x0 = xpb[(size_t)s0 * 64 + lane], x1 = xpb[(size_t)s1 * 64 + lane];
        uint32 x2 = xpb[(size_t)s2 * 64 + lane], x3 = xpb[(size_t)s3 * 64 + lane];
        uint32 x4 = xpb[(size_t)s4 * 64 + lane], x5 = xpb[(size_t)s5 * 64 + lane];
        uint32 x6 = xpb[(size_t)s6 * 64 + lane], x7 = xpb[(size_t)s7 * 64 + lane];
        uint32 x8 = xpb[(size_t)s8 * 64 + lane], x9 = xpb[(size_t)s9 * 64 + lane];
        uint32 xa = xpb[(size_t)sa * 64 + lane], xb = xpb[(size_t)sb * 64 + lane];
        uint32 xc = xpb[(size_t)sc * 64 + lane], xd = xpb[(size_t)sd * 64 + lane];
        uint32 xe = xpb[(size_t)se * 64 + lane], xf = xpb[(size_t)sf * 64 + lane];

        float e0 = __shfl(e, bb16 + 0),  e1 = __shfl(e, bb16 + 1);
        float e2 = __shfl(e, bb16 + 2),  e3 = __shfl(e, bb16 + 3);
        float e4 = __shfl(e, bb16 + 4),  e5 = __shfl(e, bb16 + 5);
        float e6 = __shfl(e, bb16 + 6),  e7 = __shfl(e, bb16 + 7);
        float e8 = __shfl(e, bb16 + 8),  e9 = __shfl(e, bb16 + 9);
        float ea = __shfl(e, bb16 + 10), eb = __shfl(e, bb16 + 11);
        float ec = __shfl(e, bb16 + 12), ed = __shfl(e, bb16 + 13);
        float ee = __shfl(e, bb16 + 14), ef = __shfl(e, bb16 + 15);

        ACC(e0, x0) ACC(e1, x1) ACC(e2, x2) ACC(e3, x3)
        ACC(e4, x4) ACC(e5, x5) ACC(e6, x6) ACC(e7, x7)
        ACC(e8, x8) ACC(e9, x9) ACC(ea, xa) ACC(eb, xb)
        ACC(ec, xc) ACC(ed, xd) ACC(ee, xe) ACC(ef, xf)
    }

    // ---- 8-edge tier ----
    const int cj8 = lane & 7;
    const int chh = (lane >> 3) & 3;
    const float st_c = s_tgt[(size_t)t * NHEAD + chh];
    const int bb8 = h * 8;
    for (; k + 8 <= d; k += 8) {
        int   sv = srcs[start + k + cj8];
        float a  = s_src[(size_t)sv * NHEAD + chh];
        float v  = a + st_c;
        float u  = v > 0.0f ? v : ELU_A * (__expf(v) - 1.0f);
        float e  = __expf(u);

        int s0 = srcs[start + k + 0], s1 = srcs[start + k + 1];
        int s2 = srcs[start + k + 2], s3 = srcs[start + k + 3];
        int s4 = srcs[start + k + 4], s5 = srcs[start + k + 5];
        int s6 = srcs[start + k + 6], s7 = srcs[start + k + 7];

        uint32 x0 = xpb[(size_t)s0 * 64 + lane], x1 = xpb[(size_t)s1 * 64 + lane];
        uint32 x2 = xpb[(size_t)s2 * 64 + lane], x3 = xpb[(size_t)s3 * 64 + lane];
        uint32 x4 = xpb[(size_t)s4 * 64 + lane], x5 = xpb[(size_t)s5 * 64 + lane];
        uint32 x6 = xpb[(size_t)s6 * 64 + lane], x7 = xpb[(size_t)s7 * 64 + lane];

        float e0 = __shfl(e, bb8 + 0), e1 = __shfl(e, bb8 + 1);
        float e2 = __shfl(e, bb8 + 2), e3 = __shfl(e, bb8 + 3);
        float e4 = __shfl(e, bb8 + 4), e5 = __shfl(e, bb8 + 5);
        float e6 = __shfl(e, bb8 + 6), e7 = __shfl(e, bb8 + 7);

        ACC(e0, x0) ACC(e1, x1) ACC(e2, x2) ACC(e3, x3)
        ACC(e4, x4) ACC(e5, x5) ACC(e6, x6) ACC(e7, x7)
    }

    // ---- scalar tail ----
    for (; k < d; ++k) {
        int   s  = srcs[start + k];
        float a  = s_src[(size_t)s * NHEAD + h];
        uint32 xv = xpb[(size_t)s * 64 + lane];
        float v = a + st_h;
        float u = v > 0.0f ? v : ELU_A * (__expf(v) - 1.0f);
        float e = __expf(u);
        ACC(e, xv)
    }
#undef ACC

    float inv = (d > 0) ? 1.0f / dsum : 0.0f;
    float2 o = make_float2(accx * inv, accy * inv);
    *(float2*)&out[(size_t)t * CH + lane * 2] = o;
}

extern "C" void kernel_launch(void* const* d_in, const int* in_sizes, int n_in,
                              void* d_out, int out_size, void* d_ws, size_t ws_size,
                              hipStream_t stream)
{
    const float* x     = (const float*)d_in[0];
    const float* W     = (const float*)d_in[1];
    const float* a_src = (const float*)d_in[2];
    const float* a_tgt = (const float*)d_in[3];
    const int*   ei    = (const int*)d_in[4];

    const int N = in_sizes[0] / FIN;      // 50000
    const int E = in_sizes[4] / 2;        // 1600000
    const int PB = (E + T_EDGES - 1) / T_EDGES;   // 782 partition blocks
    const int GB = (N + 63) / 64;                 // 782 gemm blocks

    char* ws = (char*)d_ws;
    unsigned short* xpb = (unsigned short*)ws;  ws += (size_t)N * CH * sizeof(unsigned short);
    float* s_src  = (float*)ws;                 ws += (size_t)N * NHEAD * sizeof(float);
    float* s_tgt  = (float*)ws;                 ws += (size_t)N * NHEAD * sizeof(float);
    int*   deg    = (int*)ws;                   ws += (size_t)N * sizeof(int);
    int*   bcnt   = (int*)ws;                   ws += (size_t)NB * sizeof(int);
    int*   rowptr = (int*)ws;                   ws += (size_t)N * sizeof(int);
    int*   srcs   = (int*)ws;                   ws += (size_t)E * sizeof(int);
    uint32* ebuck = (uint32*)ws;                ws += (size_t)NB * CAP * sizeof(uint32);

    float* out = (float*)d_out;
    const int2* ei2 = (const int2*)ei;

    hipMemsetAsync(bcnt, 0, (size_t)NB * sizeof(int), stream);

    mega_kernel<<<PB + GB, 256, 0, stream>>>(
        ei2, bcnt, ebuck, x, W, xpb, a_src, a_tgt, s_src, s_tgt, E, N, PB);
    fine_scatter_kernel<<<NB, 1024, 0, stream>>>(
        ebuck, bcnt, deg, rowptr, srcs, N);
    aggregate_kernel<<<(N + 3) / 4, 256, 0, stream>>>(
        srcs, rowptr, deg, s_src, s_tgt, (const uint32*)xpb, out, N);
}